// Round 20
// baseline (507.252 us; speedup 1.0000x reference)
//
#include <hip/hip_runtime.h>
#include <cstdint>
#include <cmath>

#define T_TOK 8192
#define H_DIM 1024
#define F_DIM 4096
#define NE 8
#define CAP 8192        // perm capacity per expert
#define BK 64
#define BM1 256         // gemm1 token rows per block (K=1024 -> amortize fixed costs)
#define BM 128          // gemm2 token rows per block
#define BN1 128         // gemm1 output cols per block
#define BN2 128         // gemm2 output cols per block
#define MBLK1 16        // gemm1 max M-blocks (256-row) per expert
#define MBLK 32         // gemm2 max M-blocks (128-row) per expert
#define LDK 140         // transpose LDS tile col-stride (shorts)
#define RTOK 32         // tokens per router block (atomic aggregation)

typedef __attribute__((ext_vector_type(8))) short short8v;
typedef __attribute__((ext_vector_type(4))) float f32x4;

static __device__ __forceinline__ unsigned short f2bf(float f) {
    union { float f; unsigned int u; } v; v.f = f;
    unsigned int r = v.u + 0x7FFFu + ((v.u >> 16) & 1u);  // RNE
    return (unsigned short)(r >> 16);
}

static __device__ __forceinline__ float bf2f(unsigned short u) {
    union { unsigned int i; float f; } v; v.i = ((unsigned)u) << 16; return v.f;
}

// Branch-free gelu: Abramowitz-Stegun 7.1.26 erf, |err| <= 1.5e-7.
static __device__ __forceinline__ float fast_gelu(float x) {
    const float s  = x * 0.70710678118f;
    const float as = fabsf(s);
    const float t  = __builtin_amdgcn_rcpf(fmaf(0.3275911f, as, 1.f));
    float p = fmaf(1.061405429f, t, -1.453152027f);
    p = fmaf(p, t, 1.421413741f);
    p = fmaf(p, t, -0.284496736f);
    p = fmaf(p, t, 0.254829592f);
    p = p * t;
    const float E = __expf(-as * as);
    const float erf_abs = fmaf(-p, E, 1.f);
    const float erf_s = copysignf(erf_abs, s);
    return 0.5f * x * (1.f + erf_s);
}

// async global->LDS, 16B per lane; LDS dest is wave-uniform base + lane*16,
// global src is per-lane (supports gather + pre-swizzled source).
static __device__ __forceinline__ void gl_lds16(const void* g, void* l) {
    __builtin_amdgcn_global_load_lds(
        (const __attribute__((address_space(1))) unsigned int*)g,
        (__attribute__((address_space(3))) unsigned int*)l, 16, 0, 0);
}

// 256-aligned exclusive prefix of the first e counts (NE=8, ~30 cycles).
static __device__ __forceinline__ int prefix256(const int* cnt, int e) {
    int o = 0;
    for (int q = 0; q < e; ++q) o += ((cnt[q] + 255) >> 8) << 8;
    return o;
}

// ---- shared transpose tile body: in[R][C] fp32 -> out[C][R] bf16, 128x64 ----
static __device__ __forceinline__ void transpose_tile(
    const float* __restrict__ in, unsigned short* __restrict__ out,
    int R, int C, int e, int bx, int by, unsigned short* tile_s)
{
    const int r0 = by * 128, c0 = bx * 64;
    const int colg = threadIdx.x & 15;
    const int rowg = threadIdx.x >> 4;
    const float* ip = in + (size_t)e * R * C + (size_t)r0 * C + c0;
#pragma unroll
    for (int p = 0; p < 2; ++p) {
        const int rr = (rowg + p * 16) * 4;
        const float4 v0 = *(const float4*)(ip + (size_t)(rr + 0) * C + colg * 4);
        const float4 v1 = *(const float4*)(ip + (size_t)(rr + 1) * C + colg * 4);
        const float4 v2 = *(const float4*)(ip + (size_t)(rr + 2) * C + colg * 4);
        const float4 v3 = *(const float4*)(ip + (size_t)(rr + 3) * C + colg * 4);
        const float rv[4][4] = {{v0.x, v0.y, v0.z, v0.w}, {v1.x, v1.y, v1.z, v1.w},
                                {v2.x, v2.y, v2.z, v2.w}, {v3.x, v3.y, v3.z, v3.w}};
#pragma unroll
        for (int ci = 0; ci < 4; ++ci) {
            ushort4 o;
            o.x = f2bf(rv[0][ci]); o.y = f2bf(rv[1][ci]);
            o.z = f2bf(rv[2][ci]); o.w = f2bf(rv[3][ci]);
            *(ushort4*)(tile_s + (colg * 4 + ci) * LDK + rr) = o;
        }
    }
    __syncthreads();
    unsigned short* op = out + (size_t)e * R * C + (size_t)c0 * R + r0;
#pragma unroll
    for (int p = 0; p < 4; ++p) {
        const int c = (threadIdx.x >> 4) + p * 16;
        const int s = (threadIdx.x & 15) * 8;
        const unsigned short* sp = tile_s + c * LDK + s;
        const uint2 w0 = *(const uint2*)(sp);
        const uint2 w1 = *(const uint2*)(sp + 4);
        uint4 o4; o4.x = w0.x; o4.y = w0.y; o4.z = w1.x; o4.w = w1.y;
        *(uint4*)(op + (size_t)c * R + s) = o4;
    }
}

// ====== prep: aggregated router + W1 transpose + W2 transpose (one dispatch) ======
#define G_ROUT (T_TOK / RTOK)   // 256 router blocks
#define G_TC   4096             // transpose blocks per weight tensor

__global__ __launch_bounds__(256) void prep_k(
    const float* __restrict__ x, const float* __restrict__ Wr,
    const float* __restrict__ br,
    const float* __restrict__ W1, const float* __restrict__ W2,
    int* __restrict__ cnt, int* __restrict__ perm,
    int* __restrict__ inv, float* __restrict__ tw,
    unsigned short* __restrict__ xb,
    unsigned short* __restrict__ w1t, unsigned short* __restrict__ w2t)
{
    __shared__ __align__(16) unsigned short tile_s[64 * LDK];
    __shared__ int   sh_e01[RTOK];
    __shared__ float sh_w0[RTOK];
    __shared__ int   sh_r0[RTOK], sh_r1[RTOK];
    __shared__ int   lcnt[NE], gbase[NE];
    const int bid = blockIdx.x;
    const int tid = threadIdx.x;

    if (bid >= G_ROUT) {
        if (bid < G_ROUT + G_TC) {
            // W1: [E][H=1024][F=4096] -> [E][F][H]; rbl=8 (by fast), cbl=64
            const int j = bid - G_ROUT;
            const int e = j >> 9; const int rem = j & 511;
            transpose_tile(W1, w1t, H_DIM, F_DIM, e, rem >> 3, rem & 7, tile_s);
        } else {
            // W2: [E][F=4096][H=1024] -> [E][H][F]; rbl=32 (by fast), cbl=16
            const int j = bid - G_ROUT - G_TC;
            const int e = j >> 9; const int rem = j & 511;
            transpose_tile(W2, w2t, F_DIM, H_DIM, e, rem >> 5, rem & 31, tile_s);
        }
        return;
    }

    // ---- router: 4 waves x 8 sequential tokens; logits, top-2, x->bf16 ----
    const int wave = tid >> 6;
    const int lane = tid & 63;
    if (tid < NE) lcnt[tid] = 0;
    __syncthreads();

    for (int tk = 0; tk < RTOK / 4; ++tk) {
        const int li = wave * (RTOK / 4) + tk;
        const int t = bid * RTOK + li;
        const float* xr = x + (size_t)t * H_DIM;
        float acc[NE];
#pragma unroll
        for (int e = 0; e < NE; ++e) acc[e] = 0.f;
#pragma unroll
        for (int c0 = 0; c0 < H_DIM; c0 += 256) {
            const float4 v = *(const float4*)(xr + c0 + lane * 4);
            ushort4 ob;
            ob.x = f2bf(v.x); ob.y = f2bf(v.y); ob.z = f2bf(v.z); ob.w = f2bf(v.w);
            *(ushort4*)(xb + (size_t)t * H_DIM + c0 + lane * 4) = ob;
            const int hbase = c0 + lane * 4;
            float vv[4] = {v.x, v.y, v.z, v.w};
#pragma unroll
            for (int i = 0; i < 4; ++i) {
                const float4 w0 = *(const float4*)(Wr + (size_t)(hbase + i) * NE);
                const float4 w1 = *(const float4*)(Wr + (size_t)(hbase + i) * NE + 4);
                acc[0] += vv[i] * w0.x; acc[1] += vv[i] * w0.y;
                acc[2] += vv[i] * w0.z; acc[3] += vv[i] * w0.w;
                acc[4] += vv[i] * w1.x; acc[5] += vv[i] * w1.y;
                acc[6] += vv[i] * w1.z; acc[7] += vv[i] * w1.w;
            }
        }
#pragma unroll
        for (int off = 32; off > 0; off >>= 1) {
#pragma unroll
            for (int e = 0; e < NE; ++e) acc[e] += __shfl_xor(acc[e], off, 64);
        }
        if (lane == 0) {
#pragma unroll
            for (int e = 0; e < NE; ++e) acc[e] += br[e];
            int i0 = 0; float l0 = acc[0];
#pragma unroll
            for (int e = 1; e < NE; ++e) if (acc[e] > l0) { l0 = acc[e]; i0 = e; }
            int i1 = -1; float l1 = -3.4e38f;
#pragma unroll
            for (int e = 0; e < NE; ++e) if (e != i0 && acc[e] > l1) { l1 = acc[e]; i1 = e; }
            // top-2 renormalized softmax weights from logits (exact)
            sh_e01[li] = (i0 << 3) | i1;
            sh_w0[li] = 1.f / (1.f + expf(l1 - l0));
        }
    }
    __syncthreads();

    if (tid < RTOK) {
        const int e0 = sh_e01[tid] >> 3, e1 = sh_e01[tid] & 7;
        sh_r0[tid] = atomicAdd(&lcnt[e0], 1);   // LDS atomics: local ranks
        sh_r1[tid] = atomicAdd(&lcnt[e1], 1);
    }
    __syncthreads();
    if (tid < NE) gbase[tid] = atomicAdd(&cnt[tid], lcnt[tid]);  // 8 global adds/block
    __syncthreads();
    if (tid < RTOK) {
        const int t = bid * RTOK + tid;
        const int e0 = sh_e01[tid] >> 3, e1 = sh_e01[tid] & 7;
        const int p0 = gbase[e0] + sh_r0[tid];
        const int p1 = gbase[e1] + sh_r1[tid];
        const float w0 = sh_w0[tid];
        perm[e0 * CAP + p0] = t;
        perm[e1 * CAP + p1] = t;
        inv[2 * t + 0] = (e0 << 13) | p0;  tw[2 * t + 0] = w0;
        inv[2 * t + 1] = (e1 << 13) | p1;  tw[2 * t + 1] = 1.f - w0;
    }
}

// ================= GEMM1: h = gelu(gather(x) @ W1[e] + b1[e]) =================
// 256x128 tile, 512 thr (8 waves = 2N x 4M), wave-tile 64x64, single-buffer
// BK=64 (48KB LDS, 3 blocks/CU). 2x work per block amortizes rows_s gather,
// prologue, epilogue+gelu, and tail drain over K=1024's short 16-step loop;
// staging drops to 6 VMEM issues/thread/K-step. XOR-swizzle, swapped MFMA.
__global__ __launch_bounds__(512, 2) void gemm1_k(
    const unsigned short* __restrict__ xb,   // [T][H] bf16
    const unsigned short* __restrict__ w1t,  // [E][F][H] bf16 (pre-transposed)
    const float* __restrict__ b1,            // [E][F]
    unsigned short* __restrict__ hbuf,       // [rows][F] bf16
    const int* __restrict__ perm, const int* __restrict__ cnt)
{
    __shared__ __align__(16) unsigned short smem[(BM1 + BN1) * BK];  // 48KB
    __shared__ int rows_s[BM1];

    constexpr int NY = F_DIM / BN1;            // 32
    constexpr int nwg = MBLK1 * NY * NE;       // 4096
    const int bid = blockIdx.x;
    const int wg = (bid & 7) * (nwg >> 3) + (bid >> 3);   // XCD-aware bijective swizzle
    const int e  = wg / (MBLK1 * NY);
    const int rem = wg % (MBLK1 * NY);
    const int nb = rem / MBLK1;
    const int mb = rem % MBLK1;                // fastest: same-XCD neighbors share B panel

    const int c = cnt[e];
    const int m0 = mb * BM1;
    if (m0 >= c) return;
    const int tid = threadIdx.x;

    if (tid < BM1) {
        const int i = m0 + tid;
        rows_s[tid] = perm[e * CAP + (i < c ? i : c - 1)];
    }
    __syncthreads();

    const int lane = tid & 63;
    const int w = tid >> 6;            // wave 0..7
    const int srow = tid >> 3;         // staging row-in-round 0..63
    const int u = tid & 7;             // 16B unit within 128B row
    const int us = (u ^ (srow & 7)) * 8;   // pre-swizzled source unit (shorts)

    const unsigned short* bp = w1t + ((size_t)e * F_DIM + nb * BN1) * H_DIM;
    const unsigned short* src[6];
    int dst[6];
#pragma unroll
    for (int j = 0; j < 6; ++j) {
        const int r = j * 64 + srow;   // struct rows: A = 0..255, B = 256..383
        src[j] = (j < 4) ? (xb + (size_t)rows_s[r] * H_DIM + us)
                         : (bp + (size_t)(r - BM1) * H_DIM + us);
        dst[j] = (j * 64 + w * 8) * BK + lane * 8;   // wave-uniform + lane*16B
    }

    f32x4 acc[4][4];
#pragma unroll
    for (int m = 0; m < 4; ++m)
#pragma unroll
        for (int n = 0; n < 4; ++n) acc[m][n] = (f32x4){0.f, 0.f, 0.f, 0.f};

    const int wq = w & 3;              // token quarter (0..3)
    const int wn = w >> 2;             // f half (0..1)
    const int fr = lane & 15;
    const int fg = lane >> 4;
    const int fx = fr & 7;

    for (int k0 = 0; k0 < H_DIM; k0 += BK) {
#pragma unroll
        for (int j = 0; j < 6; ++j) gl_lds16(src[j] + k0, smem + dst[j]);
        __syncthreads();   // drains vmcnt + barrier
        const unsigned short* A = smem;
        const unsigned short* B = smem + BM1 * BK;
#pragma unroll
        for (int kk = 0; kk < 2; ++kk) {
            const int q = kk * 4 + fg;
            const int ua = (q ^ fx) * 8;
            short8v a[4], b[4];
#pragma unroll
            for (int m = 0; m < 4; ++m)
                a[m] = *(const short8v*)(A + (wq * 64 + m * 16 + fr) * BK + ua);
#pragma unroll
            for (int n = 0; n < 4; ++n)
                b[n] = *(const short8v*)(B + (wn * 64 + n * 16 + fr) * BK + ua);
#pragma unroll
            for (int m = 0; m < 4; ++m)
#pragma unroll
                for (int n = 0; n < 4; ++n)   // swapped: C[f][token]
                    acc[m][n] = __builtin_amdgcn_mfma_f32_16x16x32_bf16(b[n], a[m], acc[m][n], 0, 0, 0);
        }
        __syncthreads();
    }

    // epilogue: thread holds 4 consecutive f at fixed token -> packed 8B stores
    const size_t hrow0 = (size_t)prefix256(cnt, e) + m0;
#pragma unroll
    for (int n = 0; n < 4; ++n) {
        const int f = nb * BN1 + wn * 64 + n * 16 + fg * 4;
        const float4 bv = *(const float4*)(b1 + e * F_DIM + f);
        const float bb[4] = {bv.x, bv.y, bv.z, bv.w};
#pragma unroll
        for (int m = 0; m < 4; ++m) {
            const int tl = wq * 64 + m * 16 + fr;
            ushort4 o;
#pragma unroll
            for (int r = 0; r < 4; ++r) {
                const float g = fast_gelu(acc[m][n][r] + bb[r]);
                ((unsigned short*)&o)[r] = f2bf(g);
            }
            *(ushort4*)(hbuf + (hrow0 + tl) * F_DIM + f) = o;
        }
    }
}

// ======= GEMM2: ybuf[row] = h @ W2[e] + b2[e] (bf16, no atomics), BN2=128 =======
__global__ __launch_bounds__(256, 2) void gemm2_k(
    const unsigned short* __restrict__ hbuf, // [rows][F] bf16
    const unsigned short* __restrict__ w2t,  // [E][H][F] bf16 (pre-transposed)
    const float* __restrict__ b2,            // [E][H]
    unsigned short* __restrict__ ybuf,       // [rows][H] bf16
    const int* __restrict__ cnt)
{
    __shared__ __align__(16) unsigned short smem[(BM + BN2) * BK];  // 32KB

    constexpr int NY = H_DIM / BN2;            // 8
    constexpr int nwg = MBLK * NY * NE;        // 2048
    const int bid = blockIdx.x;
    const int wg = (bid & 7) * (nwg >> 3) + (bid >> 3);
    const int e  = wg / (MBLK * NY);
    const int rem = wg % (MBLK * NY);
    const int nb = rem / MBLK;
    const int mb = rem % MBLK;

    const int c = cnt[e];
    const int m0 = mb * BM;
    if (m0 >= c) return;
    const int tid = threadIdx.x;

    const int lane = tid & 63;
    const int w = tid >> 6;
    const int srow = tid >> 3;
    const int u = tid & 7;
    const int us = (u ^ (srow & 7)) * 8;

    const size_t arow0 = (size_t)prefix256(cnt, e) + m0;
    const unsigned short* bp = w2t + ((size_t)e * H_DIM + nb * BN2) * F_DIM;
    const unsigned short* srcA[4];
    const unsigned short* srcB[4];
    int dstA[4], dstB[4];
#pragma unroll
    for (int j = 0; j < 4; ++j) {
        srcA[j] = hbuf + (arow0 + j * 32 + srow) * F_DIM + us;
        dstA[j] = (j * 32 + w * 8) * BK + lane * 8;
        srcB[j] = bp + (size_t)(j * 32 + srow) * F_DIM + us;
        dstB[j] = BM * BK + dstA[j];
    }

    f32x4 acc[4][4];
#pragma unroll
    for (int m = 0; m < 4; ++m)
#pragma unroll
        for (int n = 0; n < 4; ++n) acc[m][n] = (f32x4){0.f, 0.f, 0.f, 0.f};

    const int wr = (tid >> 7) & 1;     // token half
    const int wc = (tid >> 6) & 1;     // h half
    const int fr = lane & 15;
    const int fg = lane >> 4;
    const int fx = fr & 7;

    for (int k0 = 0; k0 < F_DIM; k0 += BK) {
#pragma unroll
        for (int j = 0; j < 4; ++j) gl_lds16(srcA[j] + k0, smem + dstA[j]);
#pragma unroll
        for (int j = 0; j < 4; ++j) gl_lds16(srcB[j] + k0, smem + dstB[j]);
        __syncthreads();
        const unsigned short* A = smem;
        const unsigned short* B = smem + BM * BK;
#pragma unroll
        for (int kk = 0; kk < 2; ++kk) {
            const int q = kk * 4 + fg;
            const int ua = (q ^ fx) * 8;
            short8v a[4], b[4];
#pragma unroll
            for (int m = 0; m < 4; ++m)
                a[m] = *(const short8v*)(A + (wr * 64 + m * 16 + fr) * BK + ua);
#pragma unroll
            for (int n = 0; n < 4; ++n)
                b[n] = *(const short8v*)(B + (wc * 64 + n * 16 + fr) * BK + ua);
#pragma unroll
            for (int m = 0; m < 4; ++m)
#pragma unroll
                for (int n = 0; n < 4; ++n)   // swapped: C[h][token]
                    acc[m][n] = __builtin_amdgcn_mfma_f32_16x16x32_bf16(b[n], a[m], acc[m][n], 0, 0, 0);
        }
        __syncthreads();
    }

    // epilogue: packed bf16 ushort4 stores (bias folded; weights in combine_k)
#pragma unroll
    for (int n = 0; n < 4; ++n) {
        const int h = nb * BN2 + wc * 64 + n * 16 + fg * 4;
        const float4 bv = *(const float4*)(b2 + e * H_DIM + h);
#pragma unroll
        for (int m = 0; m < 4; ++m) {
            const int tl = wr * 64 + m * 16 + fr;
            ushort4 o;
            o.x = f2bf(acc[m][n][0] + bv.x);
            o.y = f2bf(acc[m][n][1] + bv.y);
            o.z = f2bf(acc[m][n][2] + bv.z);
            o.w = f2bf(acc[m][n][3] + bv.w);
            *(ushort4*)(ybuf + (arow0 + tl) * H_DIM + h) = o;
        }
    }
}

// ---------------- combine: out[t] = w0*y[slot0] + w1*y[slot1] ----------------
__global__ __launch_bounds__(256) void combine_k(
    const unsigned short* __restrict__ ybuf, const int* __restrict__ inv,
    const float* __restrict__ tw, const int* __restrict__ cnt,
    float* __restrict__ out)
{
    const int t = blockIdx.x;
    const int j = threadIdx.x;          // 256 threads x 4 bf16 = 1024 = H
    const int i0 = inv[2 * t], i1 = inv[2 * t + 1];
    const float w0 = tw[2 * t], w1 = tw[2 * t + 1];
    const size_t r0 = (size_t)prefix256(cnt, i0 >> 13) + (i0 & 8191);
    const size_t r1 = (size_t)prefix256(cnt, i1 >> 13) + (i1 & 8191);
    const ushort4 a = *(const ushort4*)(ybuf + r0 * H_DIM + j * 4);
    const ushort4 b = *(const ushort4*)(ybuf + r1 * H_DIM + j * 4);
    float4 o;
    o.x = w0 * bf2f(a.x) + w1 * bf2f(b.x);
    o.y = w0 * bf2f(a.y) + w1 * bf2f(b.y);
    o.z = w0 * bf2f(a.z) + w1 * bf2f(b.z);
    o.w = w0 * bf2f(a.w) + w1 * bf2f(b.w);
    *(float4*)(out + (size_t)t * H_DIM + j * 4) = o;
}

extern "C" void kernel_launch(void* const* d_in, const int* in_sizes, int n_in,
                              void* d_out, int out_size, void* d_ws, size_t ws_size,
                              hipStream_t stream)
{
    const float* x  = (const float*)d_in[0];
    const float* Wr = (const float*)d_in[1];
    const float* br = (const float*)d_in[2];
    const float* W1 = (const float*)d_in[3];
    const float* b1 = (const float*)d_in[4];
    const float* W2 = (const float*)d_in[5];
    const float* b2 = (const float*)d_in[6];
    float* out = (float*)d_out;

    char* ws = (char*)d_ws;
    size_t off = 0;
    auto alloc = [&](size_t bytes) {
        char* p = ws + off;
        off += (bytes + 255) & ~(size_t)255;
        return p;
    };
    // Order matters: ybuf aliases w1t (dead after gemm1 completes).
    unsigned short* w2t  = (unsigned short*)alloc((size_t)NE * H_DIM * F_DIM * 2);  // 67 MB
    unsigned short* w1t  = (unsigned short*)alloc((size_t)NE * F_DIM * H_DIM * 2);  // 67 MB
    unsigned short* xb   = (unsigned short*)alloc((size_t)T_TOK * H_DIM * 2);       // 17 MB
    unsigned short* hbuf = (unsigned short*)alloc((size_t)(T_TOK * 2 + NE * BM1) * F_DIM * 2); // 151 MB
    int*   cnt  = (int*)alloc(NE * 4);
    int*   perm = (int*)alloc((size_t)NE * CAP * 4);
    int*   inv  = (int*)alloc((size_t)T_TOK * 2 * 4);
    float* tw   = (float*)alloc((size_t)T_TOK * 2 * 4);
    unsigned short* ybuf = w1t;   // [rows][H] bf16, 37.7 MB < w1t (67 MB)
    (void)ws_size; (void)in_sizes; (void)n_in; (void)out_size;

    hipMemsetAsync(cnt, 0, NE * 4, stream);
    prep_k<<<G_ROUT + 2 * G_TC, 256, 0, stream>>>(x, Wr, br, W1, W2,
                                                  cnt, perm, inv, tw, xb, w1t, w2t);
    gemm1_k<<<MBLK1 * (F_DIM / BN1) * NE, 512, 0, stream>>>(xb, w1t, b1, hbuf, perm, cnt);
    gemm2_k<<<MBLK * (H_DIM / BN2) * NE, 256, 0, stream>>>(hbuf, w2t, b2, ybuf, cnt);
    combine_k<<<T_TOK, 256, 0, stream>>>(ybuf, inv, tw, cnt, out);
}

// Round 21
// 473.675 us; speedup vs baseline: 1.0709x; 1.0709x over previous
//
#include <hip/hip_runtime.h>
#include <cstdint>
#include <cmath>

#define T_TOK 8192
#define H_DIM 1024
#define F_DIM 4096
#define NE 8
#define CAP 8192        // perm capacity per expert
#define BK 64
#define BM 128          // token rows per block
#define BN 256          // gemm1 output cols per block
#define BN2 128         // gemm2 output cols per block
#define MBLK 32         // max M-blocks (128-row) per expert (4096-token cap)
#define LDK 140         // transpose LDS tile col-stride (shorts)
#define RTOK 32         // tokens per router block (atomic aggregation)

typedef __attribute__((ext_vector_type(8))) short short8v;
typedef __attribute__((ext_vector_type(4))) float f32x4;

static __device__ __forceinline__ unsigned short f2bf(float f) {
    union { float f; unsigned int u; } v; v.f = f;
    unsigned int r = v.u + 0x7FFFu + ((v.u >> 16) & 1u);  // RNE
    return (unsigned short)(r >> 16);
}

static __device__ __forceinline__ float bf2f(unsigned short u) {
    union { unsigned int i; float f; } v; v.i = ((unsigned)u) << 16; return v.f;
}

// Branch-free gelu: Abramowitz-Stegun 7.1.26 erf, |err| <= 1.5e-7.
static __device__ __forceinline__ float fast_gelu(float x) {
    const float s  = x * 0.70710678118f;
    const float as = fabsf(s);
    const float t  = __builtin_amdgcn_rcpf(fmaf(0.3275911f, as, 1.f));
    float p = fmaf(1.061405429f, t, -1.453152027f);
    p = fmaf(p, t, 1.421413741f);
    p = fmaf(p, t, -0.284496736f);
    p = fmaf(p, t, 0.254829592f);
    p = p * t;
    const float E = __expf(-as * as);
    const float erf_abs = fmaf(-p, E, 1.f);
    const float erf_s = copysignf(erf_abs, s);
    return 0.5f * x * (1.f + erf_s);
}

// async global->LDS, 16B per lane; LDS dest is wave-uniform base + lane*16,
// global src is per-lane (supports gather + pre-swizzled source).
static __device__ __forceinline__ void gl_lds16(const void* g, void* l) {
    __builtin_amdgcn_global_load_lds(
        (const __attribute__((address_space(1))) unsigned int*)g,
        (__attribute__((address_space(3))) unsigned int*)l, 16, 0, 0);
}

// 128-aligned exclusive prefix of the first e counts (NE=8, ~30 cycles).
static __device__ __forceinline__ int prefix128(const int* cnt, int e) {
    int o = 0;
    for (int q = 0; q < e; ++q) o += ((cnt[q] + 127) >> 7) << 7;
    return o;
}

// ---- shared transpose tile body: in[R][C] fp32 -> out[C][R] bf16, 128x64 ----
static __device__ __forceinline__ void transpose_tile(
    const float* __restrict__ in, unsigned short* __restrict__ out,
    int R, int C, int e, int bx, int by, unsigned short* tile_s)
{
    const int r0 = by * 128, c0 = bx * 64;
    const int colg = threadIdx.x & 15;
    const int rowg = threadIdx.x >> 4;
    const float* ip = in + (size_t)e * R * C + (size_t)r0 * C + c0;
#pragma unroll
    for (int p = 0; p < 2; ++p) {
        const int rr = (rowg + p * 16) * 4;
        const float4 v0 = *(const float4*)(ip + (size_t)(rr + 0) * C + colg * 4);
        const float4 v1 = *(const float4*)(ip + (size_t)(rr + 1) * C + colg * 4);
        const float4 v2 = *(const float4*)(ip + (size_t)(rr + 2) * C + colg * 4);
        const float4 v3 = *(const float4*)(ip + (size_t)(rr + 3) * C + colg * 4);
        const float rv[4][4] = {{v0.x, v0.y, v0.z, v0.w}, {v1.x, v1.y, v1.z, v1.w},
                                {v2.x, v2.y, v2.z, v2.w}, {v3.x, v3.y, v3.z, v3.w}};
#pragma unroll
        for (int ci = 0; ci < 4; ++ci) {
            ushort4 o;
            o.x = f2bf(rv[0][ci]); o.y = f2bf(rv[1][ci]);
            o.z = f2bf(rv[2][ci]); o.w = f2bf(rv[3][ci]);
            *(ushort4*)(tile_s + (colg * 4 + ci) * LDK + rr) = o;
        }
    }
    __syncthreads();
    unsigned short* op = out + (size_t)e * R * C + (size_t)c0 * R + r0;
#pragma unroll
    for (int p = 0; p < 4; ++p) {
        const int c = (threadIdx.x >> 4) + p * 16;
        const int s = (threadIdx.x & 15) * 8;
        const unsigned short* sp = tile_s + c * LDK + s;
        const uint2 w0 = *(const uint2*)(sp);
        const uint2 w1 = *(const uint2*)(sp + 4);
        uint4 o4; o4.x = w0.x; o4.y = w0.y; o4.z = w1.x; o4.w = w1.y;
        *(uint4*)(op + (size_t)c * R + s) = o4;
    }
}

// ============ prep: aggregated router + W1 transpose (one dispatch) ============
// Router: 32 tokens/block, choices buffered in LDS, local ranks via LDS
// atomics, then only 8 GLOBAL fetch-adds per block -> same-address atomic
// chain 2048 -> ~256 per counter (was the hidden serialization in r8-r14).
#define G_ROUT (T_TOK / RTOK)   // 256 router blocks
#define G_TC   4096             // W1 transpose blocks

__global__ __launch_bounds__(256) void prep_k(
    const float* __restrict__ x, const float* __restrict__ Wr,
    const float* __restrict__ br, const float* __restrict__ W1,
    int* __restrict__ cnt, int* __restrict__ perm,
    int* __restrict__ inv, float* __restrict__ tw,
    unsigned short* __restrict__ xb, unsigned short* __restrict__ w1t)
{
    __shared__ __align__(16) unsigned short tile_s[64 * LDK];
    __shared__ int   sh_e01[RTOK];
    __shared__ float sh_w0[RTOK];
    __shared__ int   sh_r0[RTOK], sh_r1[RTOK];
    __shared__ int   lcnt[NE], gbase[NE];
    const int bid = blockIdx.x;
    const int tid = threadIdx.x;

    if (bid >= G_ROUT) {
        // W1: [E][H=1024][F=4096] -> [E][F][H]; rbl=8 (by fast), cbl=64
        const int j = bid - G_ROUT;
        const int e = j >> 9; const int rem = j & 511;
        transpose_tile(W1, w1t, H_DIM, F_DIM, e, rem >> 3, rem & 7, tile_s);
        return;
    }

    // ---- router: 4 waves x 8 sequential tokens; logits, top-2, x->bf16 ----
    const int wave = tid >> 6;
    const int lane = tid & 63;
    if (tid < NE) lcnt[tid] = 0;
    __syncthreads();

    for (int tk = 0; tk < RTOK / 4; ++tk) {
        const int li = wave * (RTOK / 4) + tk;
        const int t = bid * RTOK + li;
        const float* xr = x + (size_t)t * H_DIM;
        float acc[NE];
#pragma unroll
        for (int e = 0; e < NE; ++e) acc[e] = 0.f;
#pragma unroll
        for (int c0 = 0; c0 < H_DIM; c0 += 256) {
            const float4 v = *(const float4*)(xr + c0 + lane * 4);
            ushort4 ob;
            ob.x = f2bf(v.x); ob.y = f2bf(v.y); ob.z = f2bf(v.z); ob.w = f2bf(v.w);
            *(ushort4*)(xb + (size_t)t * H_DIM + c0 + lane * 4) = ob;
            const int hbase = c0 + lane * 4;
            float vv[4] = {v.x, v.y, v.z, v.w};
#pragma unroll
            for (int i = 0; i < 4; ++i) {
                const float4 w0 = *(const float4*)(Wr + (size_t)(hbase + i) * NE);
                const float4 w1 = *(const float4*)(Wr + (size_t)(hbase + i) * NE + 4);
                acc[0] += vv[i] * w0.x; acc[1] += vv[i] * w0.y;
                acc[2] += vv[i] * w0.z; acc[3] += vv[i] * w0.w;
                acc[4] += vv[i] * w1.x; acc[5] += vv[i] * w1.y;
                acc[6] += vv[i] * w1.z; acc[7] += vv[i] * w1.w;
            }
        }
#pragma unroll
        for (int off = 32; off > 0; off >>= 1) {
#pragma unroll
            for (int e = 0; e < NE; ++e) acc[e] += __shfl_xor(acc[e], off, 64);
        }
        if (lane == 0) {
#pragma unroll
            for (int e = 0; e < NE; ++e) acc[e] += br[e];
            int i0 = 0; float l0 = acc[0];
#pragma unroll
            for (int e = 1; e < NE; ++e) if (acc[e] > l0) { l0 = acc[e]; i0 = e; }
            int i1 = -1; float l1 = -3.4e38f;
#pragma unroll
            for (int e = 0; e < NE; ++e) if (e != i0 && acc[e] > l1) { l1 = acc[e]; i1 = e; }
            // top-2 renormalized softmax weights from logits (exact)
            sh_e01[li] = (i0 << 3) | i1;
            sh_w0[li] = 1.f / (1.f + expf(l1 - l0));
        }
    }
    __syncthreads();

    if (tid < RTOK) {
        const int e0 = sh_e01[tid] >> 3, e1 = sh_e01[tid] & 7;
        sh_r0[tid] = atomicAdd(&lcnt[e0], 1);   // LDS atomics: local ranks
        sh_r1[tid] = atomicAdd(&lcnt[e1], 1);
    }
    __syncthreads();
    if (tid < NE) gbase[tid] = atomicAdd(&cnt[tid], lcnt[tid]);  // 8 global adds/block
    __syncthreads();
    if (tid < RTOK) {
        const int t = bid * RTOK + tid;
        const int e0 = sh_e01[tid] >> 3, e1 = sh_e01[tid] & 7;
        const int p0 = gbase[e0] + sh_r0[tid];
        const int p1 = gbase[e1] + sh_r1[tid];
        const float w0 = sh_w0[tid];
        perm[e0 * CAP + p0] = t;
        perm[e1 * CAP + p1] = t;
        inv[2 * t + 0] = (e0 << 13) | p0;  tw[2 * t + 0] = w0;
        inv[2 * t + 1] = (e1 << 13) | p1;  tw[2 * t + 1] = 1.f - w0;
    }
}

// ================= GEMM1: h = gelu(gather(x) @ W1[e] + b1[e]) =================
// PROLOGUE: each block first does one 128x64 W2-transpose slice (1:1 with the
// 4096 blocks) absorbed into gemm1's spare BW. GEMM core: 128x256 tile, 4
// waves, wave-tile 64x128, single-buffer BK=64, global_load_lds, XOR-swizzled
// src+read, swapped-operand MFMA (proven core).
__global__ __launch_bounds__(256, 2) void gemm1_k(
    const unsigned short* __restrict__ xb,   // [T][H] bf16
    const unsigned short* __restrict__ w1t,  // [E][F][H] bf16 (pre-transposed)
    const float* __restrict__ b1,            // [E][F]
    const float* __restrict__ W2,            // [E][F][H] fp32
    unsigned short* __restrict__ w2t,        // [E][H][F] bf16 (out, for gemm2)
    unsigned short* __restrict__ hbuf,       // [rows][F] bf16
    const int* __restrict__ perm, const int* __restrict__ cnt)
{
    __shared__ __align__(16) unsigned short smem[(BM + BN) * BK];  // A 16KB | B 32KB
    __shared__ int rows_s[BM];

    const int bid = blockIdx.x;

    // ---- W2-T slice: [E][F=4096][H=1024] -> [E][H][F]; rbl=32 (by fast), cbl=16
    {
        const int e2 = bid >> 9; const int rem2 = bid & 511;
        transpose_tile(W2, w2t, F_DIM, H_DIM, e2, rem2 >> 5, rem2 & 31, smem);
    }

    constexpr int NY = F_DIM / BN;             // 16
    constexpr int nwg = MBLK * NY * NE;        // 4096
    const int wg = (bid & 7) * (nwg >> 3) + (bid >> 3);   // XCD-aware bijective swizzle
    const int e  = wg / (MBLK * NY);
    const int rem = wg % (MBLK * NY);
    const int nb = rem / MBLK;
    const int mb = rem % MBLK;                 // fastest: same-XCD neighbors share B panel

    const int c = cnt[e];
    const int m0 = mb * BM;
    const int tid = threadIdx.x;
    if (m0 >= c) return;

    if (tid < BM) {
        const int i = m0 + tid;
        rows_s[tid] = perm[e * CAP + (i < c ? i : c - 1)];
    }
    __syncthreads();   // orders transpose LDS reads before K-loop smem writes

    const int lane = tid & 63;
    const int w = tid >> 6;            // wave 0..3
    const int srow = tid >> 3;         // staging row-in-issue 0..31
    const int u = tid & 7;             // 16B unit within 128B row
    const int us = (u ^ (srow & 7)) * 8;   // pre-swizzled source unit (shorts)

    const unsigned short* bp = w1t + ((size_t)e * F_DIM + nb * BN) * H_DIM;
    const unsigned short* srcA[4];
    const unsigned short* srcB[8];
    int dstA[4], dstB[8];
#pragma unroll
    for (int j = 0; j < 4; ++j) {
        srcA[j] = xb + (size_t)rows_s[j * 32 + srow] * H_DIM + us;
        dstA[j] = (j * 32 + w * 8) * BK + lane * 8;          // wave-uniform LDS base
    }
#pragma unroll
    for (int j = 0; j < 8; ++j) {
        srcB[j] = bp + (size_t)(j * 32 + srow) * H_DIM + us;
        dstB[j] = BM * BK + (j * 32 + w * 8) * BK + lane * 8;
    }

    f32x4 acc[4][8];
#pragma unroll
    for (int m = 0; m < 4; ++m)
#pragma unroll
        for (int n = 0; n < 8; ++n) acc[m][n] = (f32x4){0.f, 0.f, 0.f, 0.f};

    const int wm = w >> 1;             // token half (0..1)
    const int wn = w & 1;              // f half (0..1)
    const int fr = lane & 15;
    const int fg = lane >> 4;
    const int fx = fr & 7;

    for (int k0 = 0; k0 < H_DIM; k0 += BK) {
#pragma unroll
        for (int j = 0; j < 4; ++j) gl_lds16(srcA[j] + k0, smem + dstA[j]);
#pragma unroll
        for (int j = 0; j < 8; ++j) gl_lds16(srcB[j] + k0, smem + dstB[j]);
        __syncthreads();   // drains vmcnt + barrier
        const unsigned short* A = smem;
        const unsigned short* B = smem + BM * BK;
#pragma unroll
        for (int kk = 0; kk < 2; ++kk) {
            const int q = kk * 4 + fg;
            const int ua = (q ^ fx) * 8;
            short8v a[4], b[8];
#pragma unroll
            for (int m = 0; m < 4; ++m)
                a[m] = *(const short8v*)(A + (wm * 64 + m * 16 + fr) * BK + ua);
#pragma unroll
            for (int n = 0; n < 8; ++n)
                b[n] = *(const short8v*)(B + (wn * 128 + n * 16 + fr) * BK + ua);
#pragma unroll
            for (int m = 0; m < 4; ++m)
#pragma unroll
                for (int n = 0; n < 8; ++n)   // swapped: C[f][token]
                    acc[m][n] = __builtin_amdgcn_mfma_f32_16x16x32_bf16(b[n], a[m], acc[m][n], 0, 0, 0);
        }
        __syncthreads();
    }

    // epilogue: thread holds 4 consecutive f at fixed token -> packed 8B stores
    const size_t hrow0 = (size_t)prefix128(cnt, e) + m0;
#pragma unroll
    for (int n = 0; n < 8; ++n) {
        const int f = nb * BN + wn * 128 + n * 16 + fg * 4;
        const float4 bv = *(const float4*)(b1 + e * F_DIM + f);
        const float bb[4] = {bv.x, bv.y, bv.z, bv.w};
#pragma unroll
        for (int m = 0; m < 4; ++m) {
            const int tl = wm * 64 + m * 16 + fr;
            ushort4 o;
#pragma unroll
            for (int r = 0; r < 4; ++r) {
                const float g = fast_gelu(acc[m][n][r] + bb[r]);
                ((unsigned short*)&o)[r] = f2bf(g);
            }
            *(ushort4*)(hbuf + (hrow0 + tl) * F_DIM + f) = o;
        }
    }
}

// ======= GEMM2: ybuf[row] = h @ W2[e] + b2[e] (bf16, no atomics), BN2=128 =======
__global__ __launch_bounds__(256, 2) void gemm2_k(
    const unsigned short* __restrict__ hbuf, // [rows][F] bf16
    const unsigned short* __restrict__ w2t,  // [E][H][F] bf16 (pre-transposed)
    const float* __restrict__ b2,            // [E][H]
    unsigned short* __restrict__ ybuf,       // [rows][H] bf16
    const int* __restrict__ cnt)
{
    __shared__ __align__(16) unsigned short smem[(BM + BN2) * BK];  // 32KB

    constexpr int NY = H_DIM / BN2;            // 8
    constexpr int nwg = MBLK * NY * NE;        // 2048
    const int bid = blockIdx.x;
    const int wg = (bid & 7) * (nwg >> 3) + (bid >> 3);
    const int e  = wg / (MBLK * NY);
    const int rem = wg % (MBLK * NY);
    const int nb = rem / MBLK;
    const int mb = rem % MBLK;

    const int c = cnt[e];
    const int m0 = mb * BM;
    if (m0 >= c) return;
    const int tid = threadIdx.x;

    const int lane = tid & 63;
    const int w = tid >> 6;
    const int srow = tid >> 3;
    const int u = tid & 7;
    const int us = (u ^ (srow & 7)) * 8;

    const size_t arow0 = (size_t)prefix128(cnt, e) + m0;
    const unsigned short* bp = w2t + ((size_t)e * H_DIM + nb * BN2) * F_DIM;
    const unsigned short* srcA[4];
    const unsigned short* srcB[4];
    int dstA[4], dstB[4];
#pragma unroll
    for (int j = 0; j < 4; ++j) {
        srcA[j] = hbuf + (arow0 + j * 32 + srow) * F_DIM + us;
        dstA[j] = (j * 32 + w * 8) * BK + lane * 8;
        srcB[j] = bp + (size_t)(j * 32 + srow) * F_DIM + us;
        dstB[j] = BM * BK + dstA[j];
    }

    f32x4 acc[4][4];
#pragma unroll
    for (int m = 0; m < 4; ++m)
#pragma unroll
        for (int n = 0; n < 4; ++n) acc[m][n] = (f32x4){0.f, 0.f, 0.f, 0.f};

    const int wr = (tid >> 7) & 1;     // token half
    const int wc = (tid >> 6) & 1;     // h half
    const int fr = lane & 15;
    const int fg = lane >> 4;
    const int fx = fr & 7;

    for (int k0 = 0; k0 < F_DIM; k0 += BK) {
#pragma unroll
        for (int j = 0; j < 4; ++j) gl_lds16(srcA[j] + k0, smem + dstA[j]);
#pragma unroll
        for (int j = 0; j < 4; ++j) gl_lds16(srcB[j] + k0, smem + dstB[j]);
        __syncthreads();
        const unsigned short* A = smem;
        const unsigned short* B = smem + BM * BK;
#pragma unroll
        for (int kk = 0; kk < 2; ++kk) {
            const int q = kk * 4 + fg;
            const int ua = (q ^ fx) * 8;
            short8v a[4], b[4];
#pragma unroll
            for (int m = 0; m < 4; ++m)
                a[m] = *(const short8v*)(A + (wr * 64 + m * 16 + fr) * BK + ua);
#pragma unroll
            for (int n = 0; n < 4; ++n)
                b[n] = *(const short8v*)(B + (wc * 64 + n * 16 + fr) * BK + ua);
#pragma unroll
            for (int m = 0; m < 4; ++m)
#pragma unroll
                for (int n = 0; n < 4; ++n)   // swapped: C[h][token]
                    acc[m][n] = __builtin_amdgcn_mfma_f32_16x16x32_bf16(b[n], a[m], acc[m][n], 0, 0, 0);
        }
        __syncthreads();
    }

    // epilogue: packed bf16 ushort4 stores (bias folded; weights in combine_k)
#pragma unroll
    for (int n = 0; n < 4; ++n) {
        const int h = nb * BN2 + wc * 64 + n * 16 + fg * 4;
        const float4 bv = *(const float4*)(b2 + e * H_DIM + h);
#pragma unroll
        for (int m = 0; m < 4; ++m) {
            const int tl = wr * 64 + m * 16 + fr;
            ushort4 o;
            o.x = f2bf(acc[m][n][0] + bv.x);
            o.y = f2bf(acc[m][n][1] + bv.y);
            o.z = f2bf(acc[m][n][2] + bv.z);
            o.w = f2bf(acc[m][n][3] + bv.w);
            *(ushort4*)(ybuf + (arow0 + tl) * H_DIM + h) = o;
        }
    }
}

// ---------------- combine: out[t] = w0*y[slot0] + w1*y[slot1] ----------------
__global__ __launch_bounds__(256) void combine_k(
    const unsigned short* __restrict__ ybuf, const int* __restrict__ inv,
    const float* __restrict__ tw, const int* __restrict__ cnt,
    float* __restrict__ out)
{
    const int t = blockIdx.x;
    const int j = threadIdx.x;          // 256 threads x 4 bf16 = 1024 = H
    const int i0 = inv[2 * t], i1 = inv[2 * t + 1];
    const float w0 = tw[2 * t], w1 = tw[2 * t + 1];
    const size_t r0 = (size_t)prefix128(cnt, i0 >> 13) + (i0 & 8191);
    const size_t r1 = (size_t)prefix128(cnt, i1 >> 13) + (i1 & 8191);
    const ushort4 a = *(const ushort4*)(ybuf + r0 * H_DIM + j * 4);
    const ushort4 b = *(const ushort4*)(ybuf + r1 * H_DIM + j * 4);
    float4 o;
    o.x = w0 * bf2f(a.x) + w1 * bf2f(b.x);
    o.y = w0 * bf2f(a.y) + w1 * bf2f(b.y);
    o.z = w0 * bf2f(a.z) + w1 * bf2f(b.z);
    o.w = w0 * bf2f(a.w) + w1 * bf2f(b.w);
    *(float4*)(out + (size_t)t * H_DIM + j * 4) = o;
}

extern "C" void kernel_launch(void* const* d_in, const int* in_sizes, int n_in,
                              void* d_out, int out_size, void* d_ws, size_t ws_size,
                              hipStream_t stream)
{
    const float* x  = (const float*)d_in[0];
    const float* Wr = (const float*)d_in[1];
    const float* br = (const float*)d_in[2];
    const float* W1 = (const float*)d_in[3];
    const float* b1 = (const float*)d_in[4];
    const float* W2 = (const float*)d_in[5];
    const float* b2 = (const float*)d_in[6];
    float* out = (float*)d_out;

    char* ws = (char*)d_ws;
    size_t off = 0;
    auto alloc = [&](size_t bytes) {
        char* p = ws + off;
        off += (bytes + 255) & ~(size_t)255;
        return p;
    };
    // Order matters: ybuf aliases w1t (dead after gemm1 completes).
    unsigned short* w2t  = (unsigned short*)alloc((size_t)NE * H_DIM * F_DIM * 2);  // 67 MB
    unsigned short* w1t  = (unsigned short*)alloc((size_t)NE * F_DIM * H_DIM * 2);  // 67 MB
    unsigned short* xb   = (unsigned short*)alloc((size_t)T_TOK * H_DIM * 2);       // 17 MB
    unsigned short* hbuf = (unsigned short*)alloc((size_t)(T_TOK * 2 + NE * BM) * F_DIM * 2); // 143 MB
    int*   cnt  = (int*)alloc(NE * 4);
    int*   perm = (int*)alloc((size_t)NE * CAP * 4);
    int*   inv  = (int*)alloc((size_t)T_TOK * 2 * 4);
    float* tw   = (float*)alloc((size_t)T_TOK * 2 * 4);
    unsigned short* ybuf = w1t;   // [rows][H] bf16, 34 MB < w1t (67 MB)
    (void)ws_size; (void)in_sizes; (void)n_in; (void)out_size;

    hipMemsetAsync(cnt, 0, NE * 4, stream);
    prep_k<<<G_ROUT + G_TC, 256, 0, stream>>>(x, Wr, br, W1, cnt, perm, inv, tw, xb, w1t);
    gemm1_k<<<MBLK * (F_DIM / BN) * NE, 256, 0, stream>>>(
        xb, w1t, b1, W2, w2t, hbuf, perm, cnt);
    gemm2_k<<<MBLK * (H_DIM / BN2) * NE, 256, 0, stream>>>(hbuf, w2t, b2, ybuf, cnt);
    combine_k<<<T_TOK, 256, 0, stream>>>(ybuf, inv, tw, cnt, out);
}

// Round 22
// 466.391 us; speedup vs baseline: 1.0876x; 1.0156x over previous
//
#include <hip/hip_runtime.h>
#include <cstdint>
#include <cmath>

#define T_TOK 8192
#define H_DIM 1024
#define F_DIM 4096
#define NE 8
#define CAP 8192        // perm capacity per expert
#define BK 64
#define BM 128          // token rows per block
#define BN1 128         // gemm1 output cols per block (r19-proven residency)
#define BN2 128         // gemm2 output cols per block
#define MBLK 32         // max M-blocks (128-row) per expert (4096-token cap)
#define LDK 140         // transpose LDS tile col-stride (shorts)
#define RTOK 32         // tokens per router block (atomic aggregation)

typedef __attribute__((ext_vector_type(8))) short short8v;
typedef __attribute__((ext_vector_type(4))) float f32x4;

static __device__ __forceinline__ unsigned short f2bf(float f) {
    union { float f; unsigned int u; } v; v.f = f;
    unsigned int r = v.u + 0x7FFFu + ((v.u >> 16) & 1u);  // RNE
    return (unsigned short)(r >> 16);
}

static __device__ __forceinline__ float bf2f(unsigned short u) {
    union { unsigned int i; float f; } v; v.i = ((unsigned)u) << 16; return v.f;
}

// Branch-free gelu: Abramowitz-Stegun 7.1.26 erf, |err| <= 1.5e-7.
static __device__ __forceinline__ float fast_gelu(float x) {
    const float s  = x * 0.70710678118f;
    const float as = fabsf(s);
    const float t  = __builtin_amdgcn_rcpf(fmaf(0.3275911f, as, 1.f));
    float p = fmaf(1.061405429f, t, -1.453152027f);
    p = fmaf(p, t, 1.421413741f);
    p = fmaf(p, t, -0.284496736f);
    p = fmaf(p, t, 0.254829592f);
    p = p * t;
    const float E = __expf(-as * as);
    const float erf_abs = fmaf(-p, E, 1.f);
    const float erf_s = copysignf(erf_abs, s);
    return 0.5f * x * (1.f + erf_s);
}

// async global->LDS, 16B per lane; LDS dest is wave-uniform base + lane*16,
// global src is per-lane (supports gather + pre-swizzled source).
static __device__ __forceinline__ void gl_lds16(const void* g, void* l) {
    __builtin_amdgcn_global_load_lds(
        (const __attribute__((address_space(1))) unsigned int*)g,
        (__attribute__((address_space(3))) unsigned int*)l, 16, 0, 0);
}

// 128-aligned exclusive prefix of the first e counts (NE=8, ~30 cycles).
static __device__ __forceinline__ int prefix128(const int* cnt, int e) {
    int o = 0;
    for (int q = 0; q < e; ++q) o += ((cnt[q] + 127) >> 7) << 7;
    return o;
}

// ---- shared transpose tile body: in[R][C] fp32 -> out[C][R] bf16, 128x64 ----
static __device__ __forceinline__ void transpose_tile(
    const float* __restrict__ in, unsigned short* __restrict__ out,
    int R, int C, int e, int bx, int by, unsigned short* tile_s)
{
    const int r0 = by * 128, c0 = bx * 64;
    const int colg = threadIdx.x & 15;
    const int rowg = threadIdx.x >> 4;
    const float* ip = in + (size_t)e * R * C + (size_t)r0 * C + c0;
#pragma unroll
    for (int p = 0; p < 2; ++p) {
        const int rr = (rowg + p * 16) * 4;
        const float4 v0 = *(const float4*)(ip + (size_t)(rr + 0) * C + colg * 4);
        const float4 v1 = *(const float4*)(ip + (size_t)(rr + 1) * C + colg * 4);
        const float4 v2 = *(const float4*)(ip + (size_t)(rr + 2) * C + colg * 4);
        const float4 v3 = *(const float4*)(ip + (size_t)(rr + 3) * C + colg * 4);
        const float rv[4][4] = {{v0.x, v0.y, v0.z, v0.w}, {v1.x, v1.y, v1.z, v1.w},
                                {v2.x, v2.y, v2.z, v2.w}, {v3.x, v3.y, v3.z, v3.w}};
#pragma unroll
        for (int ci = 0; ci < 4; ++ci) {
            ushort4 o;
            o.x = f2bf(rv[0][ci]); o.y = f2bf(rv[1][ci]);
            o.z = f2bf(rv[2][ci]); o.w = f2bf(rv[3][ci]);
            *(ushort4*)(tile_s + (colg * 4 + ci) * LDK + rr) = o;
        }
    }
    __syncthreads();
    unsigned short* op = out + (size_t)e * R * C + (size_t)c0 * R + r0;
#pragma unroll
    for (int p = 0; p < 4; ++p) {
        const int c = (threadIdx.x >> 4) + p * 16;
        const int s = (threadIdx.x & 15) * 8;
        const unsigned short* sp = tile_s + c * LDK + s;
        const uint2 w0 = *(const uint2*)(sp);
        const uint2 w1 = *(const uint2*)(sp + 4);
        uint4 o4; o4.x = w0.x; o4.y = w0.y; o4.z = w1.x; o4.w = w1.y;
        *(uint4*)(op + (size_t)c * R + s) = o4;
    }
}

// ============ prep: aggregated router + W1 transpose (one dispatch) ============
#define G_ROUT (T_TOK / RTOK)   // 256 router blocks
#define G_TC   4096             // transpose slices per weight tensor

__global__ __launch_bounds__(256) void prep_k(
    const float* __restrict__ x, const float* __restrict__ Wr,
    const float* __restrict__ br, const float* __restrict__ W1,
    int* __restrict__ cnt, int* __restrict__ perm,
    int* __restrict__ inv, float* __restrict__ tw,
    unsigned short* __restrict__ xb, unsigned short* __restrict__ w1t)
{
    __shared__ __align__(16) unsigned short tile_s[64 * LDK];
    __shared__ int   sh_e01[RTOK];
    __shared__ float sh_w0[RTOK];
    __shared__ int   sh_r0[RTOK], sh_r1[RTOK];
    __shared__ int   lcnt[NE], gbase[NE];
    const int bid = blockIdx.x;
    const int tid = threadIdx.x;

    if (bid >= G_ROUT) {
        // W1: [E][H=1024][F=4096] -> [E][F][H]; rbl=8 (by fast), cbl=64
        const int j = bid - G_ROUT;
        const int e = j >> 9; const int rem = j & 511;
        transpose_tile(W1, w1t, H_DIM, F_DIM, e, rem >> 3, rem & 7, tile_s);
        return;
    }

    // ---- router: 4 waves x 8 sequential tokens; logits, top-2, x->bf16 ----
    const int wave = tid >> 6;
    const int lane = tid & 63;
    if (tid < NE) lcnt[tid] = 0;
    __syncthreads();

    for (int tk = 0; tk < RTOK / 4; ++tk) {
        const int li = wave * (RTOK / 4) + tk;
        const int t = bid * RTOK + li;
        const float* xr = x + (size_t)t * H_DIM;
        float acc[NE];
#pragma unroll
        for (int e = 0; e < NE; ++e) acc[e] = 0.f;
#pragma unroll
        for (int c0 = 0; c0 < H_DIM; c0 += 256) {
            const float4 v = *(const float4*)(xr + c0 + lane * 4);
            ushort4 ob;
            ob.x = f2bf(v.x); ob.y = f2bf(v.y); ob.z = f2bf(v.z); ob.w = f2bf(v.w);
            *(ushort4*)(xb + (size_t)t * H_DIM + c0 + lane * 4) = ob;
            const int hbase = c0 + lane * 4;
            float vv[4] = {v.x, v.y, v.z, v.w};
#pragma unroll
            for (int i = 0; i < 4; ++i) {
                const float4 w0 = *(const float4*)(Wr + (size_t)(hbase + i) * NE);
                const float4 w1 = *(const float4*)(Wr + (size_t)(hbase + i) * NE + 4);
                acc[0] += vv[i] * w0.x; acc[1] += vv[i] * w0.y;
                acc[2] += vv[i] * w0.z; acc[3] += vv[i] * w0.w;
                acc[4] += vv[i] * w1.x; acc[5] += vv[i] * w1.y;
                acc[6] += vv[i] * w1.z; acc[7] += vv[i] * w1.w;
            }
        }
#pragma unroll
        for (int off = 32; off > 0; off >>= 1) {
#pragma unroll
            for (int e = 0; e < NE; ++e) acc[e] += __shfl_xor(acc[e], off, 64);
        }
        if (lane == 0) {
#pragma unroll
            for (int e = 0; e < NE; ++e) acc[e] += br[e];
            int i0 = 0; float l0 = acc[0];
#pragma unroll
            for (int e = 1; e < NE; ++e) if (acc[e] > l0) { l0 = acc[e]; i0 = e; }
            int i1 = -1; float l1 = -3.4e38f;
#pragma unroll
            for (int e = 0; e < NE; ++e) if (e != i0 && acc[e] > l1) { l1 = acc[e]; i1 = e; }
            // top-2 renormalized softmax weights from logits (exact)
            sh_e01[li] = (i0 << 3) | i1;
            sh_w0[li] = 1.f / (1.f + expf(l1 - l0));
        }
    }
    __syncthreads();

    if (tid < RTOK) {
        const int e0 = sh_e01[tid] >> 3, e1 = sh_e01[tid] & 7;
        sh_r0[tid] = atomicAdd(&lcnt[e0], 1);   // LDS atomics: local ranks
        sh_r1[tid] = atomicAdd(&lcnt[e1], 1);
    }
    __syncthreads();
    if (tid < NE) gbase[tid] = atomicAdd(&cnt[tid], lcnt[tid]);  // 8 global adds/block
    __syncthreads();
    if (tid < RTOK) {
        const int t = bid * RTOK + tid;
        const int e0 = sh_e01[tid] >> 3, e1 = sh_e01[tid] & 7;
        const int p0 = gbase[e0] + sh_r0[tid];
        const int p1 = gbase[e1] + sh_r1[tid];
        const float w0 = sh_w0[tid];
        perm[e0 * CAP + p0] = t;
        perm[e1 * CAP + p1] = t;
        inv[2 * t + 0] = (e0 << 13) | p0;  tw[2 * t + 0] = w0;
        inv[2 * t + 1] = (e1 << 13) | p1;  tw[2 * t + 1] = 1.f - w0;
    }
}

// ================= GEMM1: h = gelu(gather(x) @ W1[e] + b1[e]) =================
// PROLOGUE on blocks bid<4096: one 128x64 W2-transpose slice (absorbed, ~22us
// total per r18-r15 differential). GEMM: 128x128 tile (r19-proven: 33KB LDS,
// 4 blocks/CU, Occ 35%), 4 waves, wave-tile 64x64, single-buffer BK=64,
// global_load_lds, XOR-swizzle, swapped-operand MFMA -> packed 8B stores.
__global__ __launch_bounds__(256, 2) void gemm1_k(
    const unsigned short* __restrict__ xb,   // [T][H] bf16
    const unsigned short* __restrict__ w1t,  // [E][F][H] bf16 (pre-transposed)
    const float* __restrict__ b1,            // [E][F]
    const float* __restrict__ W2,            // [E][F][H] fp32
    unsigned short* __restrict__ w2t,        // [E][H][F] bf16 (out, for gemm2)
    unsigned short* __restrict__ hbuf,       // [rows][F] bf16
    const int* __restrict__ perm, const int* __restrict__ cnt)
{
    __shared__ __align__(16) unsigned short smem[(BM + BN1) * BK];  // 32KB
    __shared__ int rows_s[BM];

    const int bid = blockIdx.x;
    const int tid = threadIdx.x;

    // ---- W2-T slice on first 4096 of 8192 blocks: [E][F][H] -> [E][H][F] ----
    if (bid < G_TC) {
        const int e2 = bid >> 9; const int rem2 = bid & 511;
        transpose_tile(W2, w2t, F_DIM, H_DIM, e2, rem2 >> 5, rem2 & 31, smem);
    }

    constexpr int NY = F_DIM / BN1;            // 32
    constexpr int nwg = MBLK * NY * NE;        // 8192
    const int wg = (bid & 7) * (nwg >> 3) + (bid >> 3);   // XCD-aware bijective swizzle
    const int e  = wg / (MBLK * NY);
    const int rem = wg % (MBLK * NY);
    const int nb = rem / MBLK;
    const int mb = rem % MBLK;                 // fastest: same-XCD neighbors share B panel

    const int c = cnt[e];
    const int m0 = mb * BM;
    if (m0 >= c) return;

    if (tid < BM) {
        const int i = m0 + tid;
        rows_s[tid] = perm[e * CAP + (i < c ? i : c - 1)];
    }
    __syncthreads();   // orders transpose LDS reads before K-loop smem writes

    const int lane = tid & 63;
    const int w = tid >> 6;            // wave 0..3
    const int srow = tid >> 3;         // staging row-in-issue 0..31
    const int u = tid & 7;             // 16B unit within 128B row
    const int us = (u ^ (srow & 7)) * 8;   // pre-swizzled source unit (shorts)

    const unsigned short* bp = w1t + ((size_t)e * F_DIM + nb * BN1) * H_DIM;
    const unsigned short* srcA[4];
    const unsigned short* srcB[4];
    int dstA[4], dstB[4];
#pragma unroll
    for (int j = 0; j < 4; ++j) {
        srcA[j] = xb + (size_t)rows_s[j * 32 + srow] * H_DIM + us;
        dstA[j] = (j * 32 + w * 8) * BK + lane * 8;          // wave-uniform LDS base
        srcB[j] = bp + (size_t)(j * 32 + srow) * H_DIM + us;
        dstB[j] = BM * BK + dstA[j];
    }

    f32x4 acc[4][4];
#pragma unroll
    for (int m = 0; m < 4; ++m)
#pragma unroll
        for (int n = 0; n < 4; ++n) acc[m][n] = (f32x4){0.f, 0.f, 0.f, 0.f};

    const int wr = (tid >> 7) & 1;     // token half
    const int wc = (tid >> 6) & 1;     // f half
    const int fr = lane & 15;
    const int fg = lane >> 4;
    const int fx = fr & 7;

    for (int k0 = 0; k0 < H_DIM; k0 += BK) {
#pragma unroll
        for (int j = 0; j < 4; ++j) gl_lds16(srcA[j] + k0, smem + dstA[j]);
#pragma unroll
        for (int j = 0; j < 4; ++j) gl_lds16(srcB[j] + k0, smem + dstB[j]);
        __syncthreads();   // drains vmcnt + barrier
        const unsigned short* A = smem;
        const unsigned short* B = smem + BM * BK;
#pragma unroll
        for (int kk = 0; kk < 2; ++kk) {
            const int q = kk * 4 + fg;
            const int ua = (q ^ fx) * 8;
            short8v a[4], b[4];
#pragma unroll
            for (int m = 0; m < 4; ++m)
                a[m] = *(const short8v*)(A + (wr * 64 + m * 16 + fr) * BK + ua);
#pragma unroll
            for (int n = 0; n < 4; ++n)
                b[n] = *(const short8v*)(B + (wc * 64 + n * 16 + fr) * BK + ua);
#pragma unroll
            for (int m = 0; m < 4; ++m)
#pragma unroll
                for (int n = 0; n < 4; ++n)   // swapped: C[f][token]
                    acc[m][n] = __builtin_amdgcn_mfma_f32_16x16x32_bf16(b[n], a[m], acc[m][n], 0, 0, 0);
        }
        __syncthreads();
    }

    // epilogue: thread holds 4 consecutive f at fixed token -> packed 8B stores
    const size_t hrow0 = (size_t)prefix128(cnt, e) + m0;
#pragma unroll
    for (int n = 0; n < 4; ++n) {
        const int f = nb * BN1 + wc * 64 + n * 16 + fg * 4;
        const float4 bv = *(const float4*)(b1 + e * F_DIM + f);
        const float bb[4] = {bv.x, bv.y, bv.z, bv.w};
#pragma unroll
        for (int m = 0; m < 4; ++m) {
            const int tl = wr * 64 + m * 16 + fr;
            ushort4 o;
#pragma unroll
            for (int r = 0; r < 4; ++r) {
                const float g = fast_gelu(acc[m][n][r] + bb[r]);
                ((unsigned short*)&o)[r] = f2bf(g);
            }
            *(ushort4*)(hbuf + (hrow0 + tl) * F_DIM + f) = o;
        }
    }
}

// ======= GEMM2: ybuf[row] = h @ W2[e] + b2[e] (bf16, no atomics), BN2=128 =======
__global__ __launch_bounds__(256, 2) void gemm2_k(
    const unsigned short* __restrict__ hbuf, // [rows][F] bf16
    const unsigned short* __restrict__ w2t,  // [E][H][F] bf16 (pre-transposed)
    const float* __restrict__ b2,            // [E][H]
    unsigned short* __restrict__ ybuf,       // [rows][H] bf16
    const int* __restrict__ cnt)
{
    __shared__ __align__(16) unsigned short smem[(BM + BN2) * BK];  // 32KB

    constexpr int NY = H_DIM / BN2;            // 8
    constexpr int nwg = MBLK * NY * NE;        // 2048
    const int bid = blockIdx.x;
    const int wg = (bid & 7) * (nwg >> 3) + (bid >> 3);
    const int e  = wg / (MBLK * NY);
    const int rem = wg % (MBLK * NY);
    const int nb = rem / MBLK;
    const int mb = rem % MBLK;

    const int c = cnt[e];
    const int m0 = mb * BM;
    if (m0 >= c) return;
    const int tid = threadIdx.x;

    const int lane = tid & 63;
    const int w = tid >> 6;
    const int srow = tid >> 3;
    const int u = tid & 7;
    const int us = (u ^ (srow & 7)) * 8;

    const size_t arow0 = (size_t)prefix128(cnt, e) + m0;
    const unsigned short* bp = w2t + ((size_t)e * H_DIM + nb * BN2) * F_DIM;
    const unsigned short* srcA[4];
    const unsigned short* srcB[4];
    int dstA[4], dstB[4];
#pragma unroll
    for (int j = 0; j < 4; ++j) {
        srcA[j] = hbuf + (arow0 + j * 32 + srow) * F_DIM + us;
        dstA[j] = (j * 32 + w * 8) * BK + lane * 8;
        srcB[j] = bp + (size_t)(j * 32 + srow) * F_DIM + us;
        dstB[j] = BM * BK + dstA[j];
    }

    f32x4 acc[4][4];
#pragma unroll
    for (int m = 0; m < 4; ++m)
#pragma unroll
        for (int n = 0; n < 4; ++n) acc[m][n] = (f32x4){0.f, 0.f, 0.f, 0.f};

    const int wr = (tid >> 7) & 1;     // token half
    const int wc = (tid >> 6) & 1;     // h half
    const int fr = lane & 15;
    const int fg = lane >> 4;
    const int fx = fr & 7;

    for (int k0 = 0; k0 < F_DIM; k0 += BK) {
#pragma unroll
        for (int j = 0; j < 4; ++j) gl_lds16(srcA[j] + k0, smem + dstA[j]);
#pragma unroll
        for (int j = 0; j < 4; ++j) gl_lds16(srcB[j] + k0, smem + dstB[j]);
        __syncthreads();
        const unsigned short* A = smem;
        const unsigned short* B = smem + BM * BK;
#pragma unroll
        for (int kk = 0; kk < 2; ++kk) {
            const int q = kk * 4 + fg;
            const int ua = (q ^ fx) * 8;
            short8v a[4], b[4];
#pragma unroll
            for (int m = 0; m < 4; ++m)
                a[m] = *(const short8v*)(A + (wr * 64 + m * 16 + fr) * BK + ua);
#pragma unroll
            for (int n = 0; n < 4; ++n)
                b[n] = *(const short8v*)(B + (wc * 64 + n * 16 + fr) * BK + ua);
#pragma unroll
            for (int m = 0; m < 4; ++m)
#pragma unroll
                for (int n = 0; n < 4; ++n)   // swapped: C[h][token]
                    acc[m][n] = __builtin_amdgcn_mfma_f32_16x16x32_bf16(b[n], a[m], acc[m][n], 0, 0, 0);
        }
        __syncthreads();
    }

    // epilogue: packed bf16 ushort4 stores (bias folded; weights in combine_k)
#pragma unroll
    for (int n = 0; n < 4; ++n) {
        const int h = nb * BN2 + wc * 64 + n * 16 + fg * 4;
        const float4 bv = *(const float4*)(b2 + e * H_DIM + h);
#pragma unroll
        for (int m = 0; m < 4; ++m) {
            const int tl = wr * 64 + m * 16 + fr;
            ushort4 o;
            o.x = f2bf(acc[m][n][0] + bv.x);
            o.y = f2bf(acc[m][n][1] + bv.y);
            o.z = f2bf(acc[m][n][2] + bv.z);
            o.w = f2bf(acc[m][n][3] + bv.w);
            *(ushort4*)(ybuf + (arow0 + tl) * H_DIM + h) = o;
        }
    }
}

// ---------------- combine: out[t] = w0*y[slot0] + w1*y[slot1] ----------------
__global__ __launch_bounds__(256) void combine_k(
    const unsigned short* __restrict__ ybuf, const int* __restrict__ inv,
    const float* __restrict__ tw, const int* __restrict__ cnt,
    float* __restrict__ out)
{
    const int t = blockIdx.x;
    const int j = threadIdx.x;          // 256 threads x 4 bf16 = 1024 = H
    const int i0 = inv[2 * t], i1 = inv[2 * t + 1];
    const float w0 = tw[2 * t], w1 = tw[2 * t + 1];
    const size_t r0 = (size_t)prefix128(cnt, i0 >> 13) + (i0 & 8191);
    const size_t r1 = (size_t)prefix128(cnt, i1 >> 13) + (i1 & 8191);
    const ushort4 a = *(const ushort4*)(ybuf + r0 * H_DIM + j * 4);
    const ushort4 b = *(const ushort4*)(ybuf + r1 * H_DIM + j * 4);
    float4 o;
    o.x = w0 * bf2f(a.x) + w1 * bf2f(b.x);
    o.y = w0 * bf2f(a.y) + w1 * bf2f(b.y);
    o.z = w0 * bf2f(a.z) + w1 * bf2f(b.z);
    o.w = w0 * bf2f(a.w) + w1 * bf2f(b.w);
    *(float4*)(out + (size_t)t * H_DIM + j * 4) = o;
}

extern "C" void kernel_launch(void* const* d_in, const int* in_sizes, int n_in,
                              void* d_out, int out_size, void* d_ws, size_t ws_size,
                              hipStream_t stream)
{
    const float* x  = (const float*)d_in[0];
    const float* Wr = (const float*)d_in[1];
    const float* br = (const float*)d_in[2];
    const float* W1 = (const float*)d_in[3];
    const float* b1 = (const float*)d_in[4];
    const float* W2 = (const float*)d_in[5];
    const float* b2 = (const float*)d_in[6];
    float* out = (float*)d_out;

    char* ws = (char*)d_ws;
    size_t off = 0;
    auto alloc = [&](size_t bytes) {
        char* p = ws + off;
        off += (bytes + 255) & ~(size_t)255;
        return p;
    };
    // Order matters: ybuf aliases w1t (dead after gemm1 completes).
    unsigned short* w2t  = (unsigned short*)alloc((size_t)NE * H_DIM * F_DIM * 2);  // 67 MB
    unsigned short* w1t  = (unsigned short*)alloc((size_t)NE * F_DIM * H_DIM * 2);  // 67 MB
    unsigned short* xb   = (unsigned short*)alloc((size_t)T_TOK * H_DIM * 2);       // 17 MB
    unsigned short* hbuf = (unsigned short*)alloc((size_t)(T_TOK * 2 + NE * BM) * F_DIM * 2); // 143 MB
    int*   cnt  = (int*)alloc(NE * 4);
    int*   perm = (int*)alloc((size_t)NE * CAP * 4);
    int*   inv  = (int*)alloc((size_t)T_TOK * 2 * 4);
    float* tw   = (float*)alloc((size_t)T_TOK * 2 * 4);
    unsigned short* ybuf = w1t;   // [rows][H] bf16, 34 MB < w1t (67 MB)
    (void)ws_size; (void)in_sizes; (void)n_in; (void)out_size;

    hipMemsetAsync(cnt, 0, NE * 4, stream);
    prep_k<<<G_ROUT + G_TC, 256, 0, stream>>>(x, Wr, br, W1, cnt, perm, inv, tw, xb, w1t);
    gemm1_k<<<MBLK * (F_DIM / BN1) * NE, 256, 0, stream>>>(
        xb, w1t, b1, W2, w2t, hbuf, perm, cnt);
    gemm2_k<<<MBLK * (H_DIM / BN2) * NE, 256, 0, stream>>>(hbuf, w2t, b2, ybuf, cnt);
    combine_k<<<T_TOK, 256, 0, stream>>>(ybuf, inv, tw, cnt, out);
}